// Round 5
// baseline (17045.491 us; speedup 1.0000x reference)
//
#include <hip/hip_runtime.h>
#include <math.h>

#define Nn 131072
#define Ee 524288

typedef __attribute__((ext_vector_type(8))) short short8;
typedef __attribute__((ext_vector_type(4))) float f32x4;
typedef unsigned short ushort_t;
typedef unsigned int uint32;

__device__ __forceinline__ f32x4 mfma16(short8 a, short8 b, f32x4 c) {
    return __builtin_amdgcn_mfma_f32_16x16x32_bf16(a, b, c, 0, 0, 0);
}

__device__ __forceinline__ uint32 rne_bf16(float x) {
    uint32 u = __float_as_uint(x);
    return (u + 0x7FFFu + ((u >> 16) & 1u)) >> 16;
}

// fp32 -> 3 bf16 limbs (hi, mid, lo); hi+mid+lo ~= x to ~2^-27 rel.
__device__ __forceinline__ void split3(float x, uint32& h, uint32& m, uint32& l) {
    h = rne_bf16(x);
    float hf = __uint_as_float(h << 16);
    float r1 = x - hf;
    m = rne_bf16(r1);
    float mf = __uint_as_float(m << 16);
    float r2 = r1 - mf;
    l = rne_bf16(r2);
}

// ---------------------------------------------------------------- diag / zero
__global__ void diag_kernel(float* out, float val) {
    int n = blockIdx.x * 256 + threadIdx.x;
    if (n < Nn) out[n] = (n == 0) ? val : 0.f;
}
__global__ void zero_ints(int* p, int n) {
    int i = blockIdx.x * 256 + threadIdx.x;
    if (i < n) p[i] = 0;
}

// ---------------------------------------------------------------- CSR build
__global__ void hist_kernel(const int* __restrict__ er, const int* __restrict__ ec,
                            int* __restrict__ cnt_f, int* __restrict__ cnt_b) {
    int e = blockIdx.x * 256 + threadIdx.x;
    atomicAdd(&cnt_f[er[e]], 1);
    atomicAdd(&cnt_b[ec[e]], 1);
}

__global__ __launch_bounds__(1024) void scan_kernel(const int* __restrict__ cnt,
                                                    int* __restrict__ ptr, int n) {
    __shared__ int sums[1024];
    int t = threadIdx.x;
    int chunk = n >> 10;
    int base = t * chunk;
    int s = 0;
    for (int i = 0; i < chunk; i++) s += cnt[base + i];
    sums[t] = s;
    __syncthreads();
    for (int off = 1; off < 1024; off <<= 1) {
        int v = (t >= off) ? sums[t - off] : 0;
        __syncthreads();
        sums[t] += v;
        __syncthreads();
    }
    int run = (t == 0) ? 0 : sums[t - 1];
    for (int i = 0; i < chunk; i++) { ptr[base + i] = run; run += cnt[base + i]; }
    if (t == 1023) ptr[n] = run;
}

// fill advances ptr in place; afterwards start(r) = (r ? ptr[r-1] : 0), end(r) = ptr[r]
__global__ void fill_kernel(const int* __restrict__ er, const int* __restrict__ ec,
                            int* __restrict__ ptr_f, int* __restrict__ ptr_b,
                            int* __restrict__ src_f, int* __restrict__ src_b) {
    int e = blockIdx.x * 256 + threadIdx.x;
    int r = er[e], c = ec[e];
    int p = atomicAdd(&ptr_f[r], 1); src_f[p] = c;
    int q = atomicAdd(&ptr_b[c], 1); src_b[q] = r;
}

// ---------------------------------------------------------------- weight prep
// GRU: Wt[c=4d+g][k], c<448 (28 tiles), k<100: Wih, 100<=k<200: Whh, else 0.
__global__ void prep_gru_w(const float* __restrict__ Wih, const float* __restrict__ Whh,
                           const float* __restrict__ bih, const float* __restrict__ bhh,
                           ushort_t* __restrict__ W0, ushort_t* __restrict__ W1,
                           ushort_t* __restrict__ W2, float* __restrict__ bg) {
    int gid = blockIdx.x * 256 + threadIdx.x;
    if (gid >= 448 * 224) return;
    int c = gid / 224, k = gid - c * 224;
    int d = c >> 2, g = c & 3;
    float w = 0.f;
    if (d < 100) {
        if (k < 100) {
            if (g == 0)      w = Wih[d * 100 + k];
            else if (g == 1) w = Wih[(100 + d) * 100 + k];
            else if (g == 2) w = Wih[(200 + d) * 100 + k];
        } else if (k < 200) {
            int kk = k - 100;
            if (g == 0)      w = Whh[d * 100 + kk];
            else if (g == 1) w = Whh[(100 + d) * 100 + kk];
            else if (g == 3) w = Whh[(200 + d) * 100 + kk];
        }
    }
    uint32 h, m, l; split3(w, h, m, l);
    W0[gid] = (ushort_t)h; W1[gid] = (ushort_t)m; W2[gid] = (ushort_t)l;
    if (k == 0) {
        float b = 0.f;
        if (d < 100) {
            if (g == 0)      b = bih[d] + bhh[d];
            else if (g == 1) b = bih[100 + d] + bhh[100 + d];
            else if (g == 2) b = bih[200 + d];
            else             b = bhh[200 + d];
        }
        bg[c] = b;
    }
}

// msg MLP: W1t[c<64][k<128] (c=hidden col, k=h dim), W2t[c<112][k<64]
__global__ void prep_msg_w(const float* __restrict__ W1, const float* __restrict__ b1,
                           const float* __restrict__ W2, const float* __restrict__ b2,
                           ushort_t* __restrict__ A0, ushort_t* __restrict__ A1,
                           ushort_t* __restrict__ A2, float* __restrict__ b1p,
                           ushort_t* __restrict__ B0, ushort_t* __restrict__ B1,
                           ushort_t* __restrict__ B2, float* __restrict__ b2p) {
    int gid = blockIdx.x * 256 + threadIdx.x;
    if (gid < 8192) {
        int c = gid >> 7, k = gid & 127;
        float w = (c < 50 && k < 100) ? W1[k * 50 + c] : 0.f;
        uint32 h, m, l; split3(w, h, m, l);
        A0[gid] = (ushort_t)h; A1[gid] = (ushort_t)m; A2[gid] = (ushort_t)l;
        if (k == 0) b1p[c] = (c < 50) ? b1[c] : 0.f;
    } else if (gid < 8192 + 7168) {
        int t = gid - 8192;
        int c = t >> 6, k = t & 63;
        float w = (c < 100 && k < 50) ? W2[k * 100 + c] : 0.f;
        uint32 h, m, l; split3(w, h, m, l);
        B0[t] = (ushort_t)h; B1[t] = (ushort_t)m; B2[t] = (ushort_t)l;
        if (k == 0) b2p[c] = (c < 100) ? b2[c] : 0.f;
    }
}

// ---------------------------------------------------------------- init h
__global__ void init_h_kernel(const float* __restrict__ feat, const float* __restrict__ W,
                              const float* __restrict__ b, float* __restrict__ Act) {
    int gid = blockIdx.x * 256 + threadIdx.x;   // N*100
    int n = gid / 100, d = gid - n * 100;
    float acc = b[d];
#pragma unroll
    for (int k = 0; k < 4; k++) acc += feat[n * 4 + k] * W[k * 100 + d];
    Act[(size_t)n * 200 + 100 + d] = acc;
}

// ---------------------------------------------------------------- msg MLP (MFMA)
// fm = relu(h @ W1 + b1) @ W2 + b2 ; computed transposed: D[c][n]
__global__ __launch_bounds__(256, 2) void msg_mfma(
    const float* __restrict__ Act,
    const ushort_t* __restrict__ A0, const ushort_t* __restrict__ A1,
    const ushort_t* __restrict__ A2, const float* __restrict__ b1p,
    const ushort_t* __restrict__ B0, const ushort_t* __restrict__ B1,
    const ushort_t* __restrict__ B2, const float* __restrict__ b2p,
    float* __restrict__ fm) {
    __shared__ ushort_t C1[3][64][72];
    const int tid = threadIdx.x;
    const int u = tid >> 6;          // wave = node tile
    const int lane = tid & 63;
    const int m = lane & 15, q = lane >> 4;
    const int n0 = blockIdx.x * 64;
    const int n = n0 + u * 16 + m;

    f32x4 z = {0.f, 0.f, 0.f, 0.f};
    f32x4 a1[4] = {z, z, z, z};

    for (int kc = 0; kc < 4; kc++) {
        int kb = kc * 32 + q * 8;
        const float* src = Act + (size_t)n * 200 + 100 + kb;
        float4 v0 = *(const float4*)src;
        float4 v1 = *(const float4*)(src + 4);
        float e[8] = {v0.x, v0.y, v0.z, v0.w, v1.x, v1.y, v1.z, v1.w};
        union { short8 s; uint32 u4[4]; } f0, f1, f2;
#pragma unroll
        for (int j = 0; j < 4; j++) {
            uint32 ha, ma, la, hb, mb, lb;
            split3(e[2 * j], ha, ma, la);
            split3(e[2 * j + 1], hb, mb, lb);
            f0.u4[j] = ha | (hb << 16);
            f1.u4[j] = ma | (mb << 16);
            f2.u4[j] = la | (lb << 16);
        }
#pragma unroll
        for (int t = 0; t < 4; t++) {
            int off = (t * 16 + m) * 128 + kc * 32 + q * 8;
            short8 w0 = *(const short8*)(A0 + off);
            short8 w1 = *(const short8*)(A1 + off);
            short8 w2 = *(const short8*)(A2 + off);
            a1[t] = mfma16(w0, f0.s, a1[t]);
            a1[t] = mfma16(w0, f1.s, a1[t]);
            a1[t] = mfma16(w1, f0.s, a1[t]);
            a1[t] = mfma16(w0, f2.s, a1[t]);
            a1[t] = mfma16(w2, f0.s, a1[t]);
            a1[t] = mfma16(w1, f1.s, a1[t]);
        }
    }
    // epilogue 1: relu + split -> LDS
#pragma unroll
    for (int t = 0; t < 4; t++) {
        int c0 = t * 16 + 4 * q;
        float4 bb = *(const float4*)&b1p[c0];
        float v0 = fmaxf(a1[t][0] + bb.x, 0.f);
        float v1 = fmaxf(a1[t][1] + bb.y, 0.f);
        float v2 = fmaxf(a1[t][2] + bb.z, 0.f);
        float v3 = fmaxf(a1[t][3] + bb.w, 0.f);
        uint32 h0, m0, l0, h1, m1, l1, h2, m2, l2, h3, m3, l3;
        split3(v0, h0, m0, l0); split3(v1, h1, m1, l1);
        split3(v2, h2, m2, l2); split3(v3, h3, m3, l3);
        int nl = u * 16 + m;
        *(uint2*)&C1[0][nl][c0] = make_uint2(h0 | (h1 << 16), h2 | (h3 << 16));
        *(uint2*)&C1[1][nl][c0] = make_uint2(m0 | (m1 << 16), m2 | (m3 << 16));
        *(uint2*)&C1[2][nl][c0] = make_uint2(l0 | (l1 << 16), l2 | (l3 << 16));
    }
    __syncthreads();

    f32x4 a2[7] = {z, z, z, z, z, z, z};
    for (int kc = 0; kc < 2; kc++) {
        int nl = u * 16 + m;
        short8 c0f = *(const short8*)&C1[0][nl][kc * 32 + q * 8];
        short8 c1f = *(const short8*)&C1[1][nl][kc * 32 + q * 8];
        short8 c2f = *(const short8*)&C1[2][nl][kc * 32 + q * 8];
#pragma unroll
        for (int t = 0; t < 7; t++) {
            int off = (t * 16 + m) * 64 + kc * 32 + q * 8;
            short8 w0 = *(const short8*)(B0 + off);
            short8 w1 = *(const short8*)(B1 + off);
            short8 w2 = *(const short8*)(B2 + off);
            a2[t] = mfma16(w0, c0f, a2[t]);
            a2[t] = mfma16(w0, c1f, a2[t]);
            a2[t] = mfma16(w1, c0f, a2[t]);
            a2[t] = mfma16(w0, c2f, a2[t]);
            a2[t] = mfma16(w2, c0f, a2[t]);
            a2[t] = mfma16(w1, c1f, a2[t]);
        }
    }
#pragma unroll
    for (int t = 0; t < 7; t++) {
        int c0 = t * 16 + 4 * q;
        if (c0 < 100) {
            float4 bb = *(const float4*)&b2p[c0];
            float4 o;
            o.x = a2[t][0] + bb.x; o.y = a2[t][1] + bb.y;
            o.z = a2[t][2] + bb.z; o.w = a2[t][3] + bb.w;
            *(float4*)&fm[(size_t)n * 100 + c0] = o;
        }
    }
}

// ---------------------------------------------------------------- gather (CSR)
__global__ void gather4(const float* __restrict__ fm, const int* __restrict__ ptr,
                        const int* __restrict__ idx, float* __restrict__ Act) {
    int gid = blockIdx.x * 256 + threadIdx.x;   // N*25
    int n = gid / 25, qq = (gid - n * 25) * 4;
    int s = (n == 0) ? 0 : ptr[n - 1];
    int e = ptr[n];
    float4 acc = {0.f, 0.f, 0.f, 0.f};
    for (int i = s; i < e; i++) {
        float4 v = *(const float4*)&fm[(size_t)idx[i] * 100 + qq];
        acc.x += v.x; acc.y += v.y; acc.z += v.z; acc.w += v.w;
    }
    *(float4*)&Act[(size_t)n * 200 + qq] = acc;
}

// ---------------------------------------------------------------- GRU (MFMA) v3
// 32-row blocks, 28 col-tiles (448 padded cols), 7 tiles/wave, ct = 4t+wave.
// Product-major passes, weight limbs double-buffered in registers:
//   per kc: A:w0*f0 B:w0*f1 C:w0*f2 D:w1*f0 E:w1*f1 F:w2*f0
//   w1,w2 loads issued at kc start (used 3/5 passes later); next-kc w0 after pass C.
// MFMA dependency distance = 14 (7 tiles x 2 row-frags per pass).
__global__ __launch_bounds__(256, 3) void gru_mfma(
    float* __restrict__ Act,
    const ushort_t* __restrict__ W0, const ushort_t* __restrict__ W1,
    const ushort_t* __restrict__ W2, const float* __restrict__ bg) {
    __shared__ __align__(16) uint32 Bs[2][3][32][20];
    const int tid = threadIdx.x;
    const int wave = tid >> 6;
    const int lane = tid & 63;
    const int m = lane & 15, q = lane >> 4;
    const int n0 = blockIdx.x * 32;
    const int sr = tid >> 3;            // staging row 0..31
    const int sk4 = (tid & 7) * 4;      // staging k offset (floats)
    const int cu = (tid & 7) * 2;       // staging uint col

    f32x4 z = {0.f, 0.f, 0.f, 0.f};
    f32x4 acc[7][2];
#pragma unroll
    for (int t = 0; t < 7; t++) { acc[t][0] = z; acc[t][1] = z; }

    int woff[7];
#pragma unroll
    for (int t = 0; t < 7; t++)
        woff[t] = ((t * 4 + wave) * 16 + m) * 224 + q * 8;

    const float* actrow = Act + (size_t)(n0 + sr) * 200;

#define LDCHUNK(kc, dst) do {                                   \
        int kb = (kc) * 32 + sk4;                               \
        if (kb < 200) dst = *(const float4*)(actrow + kb);      \
        else { dst.x = 0.f; dst.y = 0.f; dst.z = 0.f; dst.w = 0.f; } \
    } while (0)

#define STAGE(b, v) do {                                        \
        uint32 h0,m0,l0,h1,m1,l1,h2,m2,l2,h3,m3,l3;             \
        split3((v).x,h0,m0,l0); split3((v).y,h1,m1,l1);         \
        split3((v).z,h2,m2,l2); split3((v).w,h3,m3,l3);         \
        *(uint2*)&Bs[b][0][sr][cu] = make_uint2(h0|(h1<<16), h2|(h3<<16)); \
        *(uint2*)&Bs[b][1][sr][cu] = make_uint2(m0|(m1<<16), m2|(m3<<16)); \
        *(uint2*)&Bs[b][2][sr][cu] = make_uint2(l0|(l1<<16), l2|(l3<<16)); \
    } while (0)

#define GPASS(Wreg, bfr)                                        \
    _Pragma("unroll")                                           \
    for (int t = 0; t < 7; t++) {                               \
        acc[t][0] = mfma16(Wreg[t], (bfr)[0], acc[t][0]);       \
        acc[t][1] = mfma16(Wreg[t], (bfr)[1], acc[t][1]);       \
    }

    // stage act chunk 0
    { float4 v0; LDCHUNK(0, v0); STAGE(0, v0); }

    // preload w0 limb for kc=0 (no LDS dependency, issues before barrier)
    short8 wA[7], wB[7], wC[7];
#pragma unroll
    for (int t = 0; t < 7; t++) wA[t] = *(const short8*)(W0 + woff[t]);

    __syncthreads();

    for (int kc = 0; kc < 7; kc++) {
        const int b = kc & 1;
        const int ko = kc * 32;
        float4 nxt;
        if (kc < 6) LDCHUNK(kc + 1, nxt);
        // issue this kc's mid/lo weight limb loads (consumed passes D..F)
#pragma unroll
        for (int t = 0; t < 7; t++) wB[t] = *(const short8*)(W1 + woff[t] + ko);
#pragma unroll
        for (int t = 0; t < 7; t++) wC[t] = *(const short8*)(W2 + woff[t] + ko);

        short8 bf0[2], bft[2];
        bf0[0] = *(const short8*)&Bs[b][0][m][q * 4];
        bf0[1] = *(const short8*)&Bs[b][0][16 + m][q * 4];
        GPASS(wA, bf0);                                   // w0*f0
        bft[0] = *(const short8*)&Bs[b][1][m][q * 4];
        bft[1] = *(const short8*)&Bs[b][1][16 + m][q * 4];
        GPASS(wA, bft);                                   // w0*f1
        bft[0] = *(const short8*)&Bs[b][2][m][q * 4];
        bft[1] = *(const short8*)&Bs[b][2][16 + m][q * 4];
        GPASS(wA, bft);                                   // w0*f2
        if (kc < 6) {                                     // prefetch next-kc w0
#pragma unroll
            for (int t = 0; t < 7; t++)
                wA[t] = *(const short8*)(W0 + woff[t] + ko + 32);
        }
        GPASS(wB, bf0);                                   // w1*f0
        bft[0] = *(const short8*)&Bs[b][1][m][q * 4];
        bft[1] = *(const short8*)&Bs[b][1][16 + m][q * 4];
        GPASS(wB, bft);                                   // w1*f1
        GPASS(wC, bf0);                                   // w2*f0
        if (kc < 6) STAGE(b ^ 1, nxt);
        __syncthreads();
    }
#undef LDCHUNK
#undef STAGE
#undef GPASS

    // epilogue: gates, in-place h update
#pragma unroll
    for (int t = 0; t < 7; t++) {
        const int ct = t * 4 + wave;        // 0..27
        const int c0 = ct * 16 + 4 * q;
        const int d = ct * 4 + q;
        if (d < 100) {
            float4 b4 = *(const float4*)&bg[c0];
#pragma unroll
            for (int u = 0; u < 2; u++) {
                int n = n0 + u * 16 + m;
                float* hp = Act + (size_t)n * 200 + 100 + d;
                float hold = *hp;
                float rp = acc[t][u][0] + b4.x;
                float zp = acc[t][u][1] + b4.y;
                float np = acc[t][u][2] + b4.z;
                float hh = acc[t][u][3] + b4.w;
                float rr = 1.f / (1.f + __expf(-rp));
                float zz = 1.f / (1.f + __expf(-zp));
                float nw = tanhf(np + rr * hh);
                *hp = (1.f - zz) * nw + zz * hold;
            }
        }
    }
}

// ---------------------------------------------------------------- classifier
__global__ __launch_bounds__(256) void classifier(
    const float* __restrict__ Act, const float* __restrict__ W1,
    const float* __restrict__ b1, const float* __restrict__ W2,
    const float* __restrict__ b2, float* __restrict__ out) {
    __shared__ float Wc[3000];
    __shared__ float bc[30];
    __shared__ float w2[30];
    int tid = threadIdx.x;
    for (int i = tid; i < 3000; i += 256) Wc[i] = W1[i];
    if (tid < 30) { bc[tid] = b1[tid]; w2[tid] = W2[tid]; }
    __syncthreads();
    int n = blockIdx.x * 256 + tid;
    float a[30];
#pragma unroll
    for (int j = 0; j < 30; j++) a[j] = bc[j];
    for (int k = 0; k < 100; k++) {
        float hv = Act[(size_t)n * 200 + 100 + k];
#pragma unroll
        for (int j = 0; j < 30; j++) a[j] = fmaf(hv, Wc[k * 30 + j], a[j]);
    }
    float s = b2[0];
#pragma unroll
    for (int j = 0; j < 30; j++) s = fmaf(fmaxf(a[j], 0.f), w2[j], s);
    out[n] = s;
}

// ---------------------------------------------------------------- launch
extern "C" void kernel_launch(void* const* d_in, const int* in_sizes, int n_in,
                              void* d_out, int out_size, void* d_ws, size_t ws_size,
                              hipStream_t stream) {
    const float* feat     = (const float*)d_in[0];
    const int*   er       = (const int*)d_in[1];
    const int*   ec       = (const int*)d_in[2];
    const float* init_W   = (const float*)d_in[3];
    const float* init_b   = (const float*)d_in[4];
    const float* fmsg_W1  = (const float*)d_in[5];
    const float* fmsg_b1  = (const float*)d_in[6];
    const float* fmsg_W2  = (const float*)d_in[7];
    const float* fmsg_b2  = (const float*)d_in[8];
    const float* bmsg_W1  = (const float*)d_in[9];
    const float* bmsg_b1  = (const float*)d_in[10];
    const float* bmsg_W2  = (const float*)d_in[11];
    const float* bmsg_b2  = (const float*)d_in[12];
    const float* fgru_Wih = (const float*)d_in[13];
    const float* fgru_Whh = (const float*)d_in[14];
    const float* fgru_bih = (const float*)d_in[15];
    const float* fgru_bhh = (const float*)d_in[16];
    const float* bgru_Wih = (const float*)d_in[17];
    const float* bgru_Whh = (const float*)d_in[18];
    const float* bgru_bih = (const float*)d_in[19];
    const float* bgru_bhh = (const float*)d_in[20];
    const float* cls_W1   = (const float*)d_in[21];
    const float* cls_b1   = (const float*)d_in[22];
    const float* cls_W2   = (const float*)d_in[23];
    const float* cls_b2   = (const float*)d_in[24];
    float* out = (float*)d_out;

    float* ws = (float*)d_ws;
    size_t o = 0;
    float* Act = ws + o; o += (size_t)Nn * 200;       // [N][200] msg|h fp32
    float* fm  = ws + o; o += (size_t)Nn * 100;       // [N][100] fp32

    ushort_t* us = (ushort_t*)(ws + o);
    size_t uo = 0;
    ushort_t* fWg0 = us + uo; uo += 448 * 224;
    ushort_t* fWg1 = us + uo; uo += 448 * 224;
    ushort_t* fWg2 = us + uo; uo += 448 * 224;
    ushort_t* bWg0 = us + uo; uo += 448 * 224;
    ushort_t* bWg1 = us + uo; uo += 448 * 224;
    ushort_t* bWg2 = us + uo; uo += 448 * 224;
    ushort_t* fA0 = us + uo; uo += 8192;
    ushort_t* fA1 = us + uo; uo += 8192;
    ushort_t* fA2 = us + uo; uo += 8192;
    ushort_t* bA0 = us + uo; uo += 8192;
    ushort_t* bA1 = us + uo; uo += 8192;
    ushort_t* bA2 = us + uo; uo += 8192;
    ushort_t* fB0 = us + uo; uo += 7168;
    ushort_t* fB1 = us + uo; uo += 7168;
    ushort_t* fB2 = us + uo; uo += 7168;
    ushort_t* bB0 = us + uo; uo += 7168;
    ushort_t* bB1 = us + uo; uo += 7168;
    ushort_t* bB2 = us + uo; uo += 7168;     // uo even
    o += uo / 2;

    float* bgf  = ws + o; o += 448;
    float* bgb  = ws + o; o += 448;
    float* b1pf = ws + o; o += 64;
    float* b1pb = ws + o; o += 64;
    float* b2pf = ws + o; o += 112;
    float* b2pb = ws + o; o += 112;

    int* iws   = (int*)(ws + o);
    int* ptr_f = iws;                       // N+1
    int* ptr_b = ptr_f + (Nn + 1);          // N+1
    int* cnt   = ptr_b + (Nn + 1);          // 2N
    int* cnt_f = cnt;
    int* cnt_b = cnt + Nn;
    int* src_f = cnt + 2 * (size_t)Nn;      // E
    int* src_b = src_f + Ee;                // E

    size_t need = o * sizeof(float) +
                  (size_t)(2 * (Nn + 1) + 2 * Nn + 2 * Ee) * sizeof(int);
    if (ws_size < need) {
        diag_kernel<<<(Nn + 255) / 256, 256, 0, stream>>>(out, (float)ws_size);
        return;
    }

    // CSR build
    zero_ints<<<(2 * Nn + 255) / 256, 256, 0, stream>>>(cnt, 2 * Nn);
    hist_kernel<<<Ee / 256, 256, 0, stream>>>(er, ec, cnt_f, cnt_b);
    scan_kernel<<<1, 1024, 0, stream>>>(cnt_f, ptr_f, Nn);
    scan_kernel<<<1, 1024, 0, stream>>>(cnt_b, ptr_b, Nn);
    fill_kernel<<<Ee / 256, 256, 0, stream>>>(er, ec, ptr_f, ptr_b, src_f, src_b);

    // weight prep (split to 3 bf16 limbs)
    prep_gru_w<<<(448 * 224 + 255) / 256, 256, 0, stream>>>(
        fgru_Wih, fgru_Whh, fgru_bih, fgru_bhh, fWg0, fWg1, fWg2, bgf);
    prep_gru_w<<<(448 * 224 + 255) / 256, 256, 0, stream>>>(
        bgru_Wih, bgru_Whh, bgru_bih, bgru_bhh, bWg0, bWg1, bWg2, bgb);
    prep_msg_w<<<(15360 + 255) / 256, 256, 0, stream>>>(
        fmsg_W1, fmsg_b1, fmsg_W2, fmsg_b2, fA0, fA1, fA2, b1pf, fB0, fB1, fB2, b2pf);
    prep_msg_w<<<(15360 + 255) / 256, 256, 0, stream>>>(
        bmsg_W1, bmsg_b1, bmsg_W2, bmsg_b2, bA0, bA1, bA2, b1pb, bB0, bB1, bB2, b2pb);

    // h init
    init_h_kernel<<<(Nn * 100) / 256, 256, 0, stream>>>(feat, init_W, init_b, Act);

    const int gTile = Nn / 64;            // 2048 (msg)
    const int gGru  = Nn / 32;            // 4096 (gru)
    const int gGath = Nn * 25 / 256;      // 12800

    for (int rd = 0; rd < 20; rd++) {
        msg_mfma<<<gTile, 256, 0, stream>>>(Act, fA0, fA1, fA2, b1pf, fB0, fB1, fB2, b2pf, fm);
        gather4<<<gGath, 256, 0, stream>>>(fm, ptr_f, src_f, Act);
        gru_mfma<<<gGru, 256, 0, stream>>>(Act, fWg0, fWg1, fWg2, bgf);

        msg_mfma<<<gTile, 256, 0, stream>>>(Act, bA0, bA1, bA2, b1pb, bB0, bB1, bB2, b2pb, fm);
        gather4<<<gGath, 256, 0, stream>>>(fm, ptr_b, src_b, Act);
        gru_mfma<<<gGru, 256, 0, stream>>>(Act, bWg0, bWg1, bWg2, bgb);
    }

    classifier<<<Nn / 256, 256, 0, stream>>>(Act, cls_W1, cls_b1, cls_W2, cls_b2, out);
}

// Round 6
// 13678.058 us; speedup vs baseline: 1.2462x; 1.2462x over previous
//
#include <hip/hip_runtime.h>
#include <math.h>

#define Nn 131072
#define Ee 524288

typedef __attribute__((ext_vector_type(8))) short short8;
typedef __attribute__((ext_vector_type(4))) float f32x4;
typedef unsigned short ushort_t;
typedef unsigned int uint32;

__device__ __forceinline__ f32x4 mfma16(short8 a, short8 b, f32x4 c) {
    return __builtin_amdgcn_mfma_f32_16x16x32_bf16(a, b, c, 0, 0, 0);
}

__device__ __forceinline__ uint32 rne_bf16(float x) {
    uint32 u = __float_as_uint(x);
    return (u + 0x7FFFu + ((u >> 16) & 1u)) >> 16;
}

// fp32 -> 3 bf16 limbs (hi, mid, lo); hi+mid+lo ~= x to ~2^-27 rel.
__device__ __forceinline__ void split3(float x, uint32& h, uint32& m, uint32& l) {
    h = rne_bf16(x);
    float hf = __uint_as_float(h << 16);
    float r1 = x - hf;
    m = rne_bf16(r1);
    float mf = __uint_as_float(m << 16);
    float r2 = r1 - mf;
    l = rne_bf16(r2);
}

// ---------------------------------------------------------------- diag / zero
__global__ void diag_kernel(float* out, float val) {
    int n = blockIdx.x * 256 + threadIdx.x;
    if (n < Nn) out[n] = (n == 0) ? val : 0.f;
}
__global__ void zero_ints(int* p, int n) {
    int i = blockIdx.x * 256 + threadIdx.x;
    if (i < n) p[i] = 0;
}

// ---------------------------------------------------------------- CSR build
__global__ void hist_kernel(const int* __restrict__ er, const int* __restrict__ ec,
                            int* __restrict__ cnt_f, int* __restrict__ cnt_b) {
    int e = blockIdx.x * 256 + threadIdx.x;
    atomicAdd(&cnt_f[er[e]], 1);
    atomicAdd(&cnt_b[ec[e]], 1);
}

__global__ __launch_bounds__(1024) void scan_kernel(const int* __restrict__ cnt,
                                                    int* __restrict__ ptr, int n) {
    __shared__ int sums[1024];
    int t = threadIdx.x;
    int chunk = n >> 10;
    int base = t * chunk;
    int s = 0;
    for (int i = 0; i < chunk; i++) s += cnt[base + i];
    sums[t] = s;
    __syncthreads();
    for (int off = 1; off < 1024; off <<= 1) {
        int v = (t >= off) ? sums[t - off] : 0;
        __syncthreads();
        sums[t] += v;
        __syncthreads();
    }
    int run = (t == 0) ? 0 : sums[t - 1];
    for (int i = 0; i < chunk; i++) { ptr[base + i] = run; run += cnt[base + i]; }
    if (t == 1023) ptr[n] = run;
}

// fill advances ptr in place; afterwards start(r) = (r ? ptr[r-1] : 0), end(r) = ptr[r]
__global__ void fill_kernel(const int* __restrict__ er, const int* __restrict__ ec,
                            int* __restrict__ ptr_f, int* __restrict__ ptr_b,
                            int* __restrict__ src_f, int* __restrict__ src_b) {
    int e = blockIdx.x * 256 + threadIdx.x;
    int r = er[e], c = ec[e];
    int p = atomicAdd(&ptr_f[r], 1); src_f[p] = c;
    int q = atomicAdd(&ptr_b[c], 1); src_b[q] = r;
}

// ---------------------------------------------------------------- weight prep
// GRU: Wt[c=4d+g][k], c<448 (28 tiles), k<100: Wih, 100<=k<200: Whh, else 0.
__global__ void prep_gru_w(const float* __restrict__ Wih, const float* __restrict__ Whh,
                           const float* __restrict__ bih, const float* __restrict__ bhh,
                           ushort_t* __restrict__ W0, ushort_t* __restrict__ W1,
                           ushort_t* __restrict__ W2, float* __restrict__ bg) {
    int gid = blockIdx.x * 256 + threadIdx.x;
    if (gid >= 448 * 224) return;
    int c = gid / 224, k = gid - c * 224;
    int d = c >> 2, g = c & 3;
    float w = 0.f;
    if (d < 100) {
        if (k < 100) {
            if (g == 0)      w = Wih[d * 100 + k];
            else if (g == 1) w = Wih[(100 + d) * 100 + k];
            else if (g == 2) w = Wih[(200 + d) * 100 + k];
        } else if (k < 200) {
            int kk = k - 100;
            if (g == 0)      w = Whh[d * 100 + kk];
            else if (g == 1) w = Whh[(100 + d) * 100 + kk];
            else if (g == 3) w = Whh[(200 + d) * 100 + kk];
        }
    }
    uint32 h, m, l; split3(w, h, m, l);
    W0[gid] = (ushort_t)h; W1[gid] = (ushort_t)m; W2[gid] = (ushort_t)l;
    if (k == 0) {
        float b = 0.f;
        if (d < 100) {
            if (g == 0)      b = bih[d] + bhh[d];
            else if (g == 1) b = bih[100 + d] + bhh[100 + d];
            else if (g == 2) b = bih[200 + d];
            else             b = bhh[200 + d];
        }
        bg[c] = b;
    }
}

// msg MLP: W1t[c<64][k<128] (c=hidden col, k=h dim), W2t[c<112][k<64]
__global__ void prep_msg_w(const float* __restrict__ W1, const float* __restrict__ b1,
                           const float* __restrict__ W2, const float* __restrict__ b2,
                           ushort_t* __restrict__ A0, ushort_t* __restrict__ A1,
                           ushort_t* __restrict__ A2, float* __restrict__ b1p,
                           ushort_t* __restrict__ B0, ushort_t* __restrict__ B1,
                           ushort_t* __restrict__ B2, float* __restrict__ b2p) {
    int gid = blockIdx.x * 256 + threadIdx.x;
    if (gid < 8192) {
        int c = gid >> 7, k = gid & 127;
        float w = (c < 50 && k < 100) ? W1[k * 50 + c] : 0.f;
        uint32 h, m, l; split3(w, h, m, l);
        A0[gid] = (ushort_t)h; A1[gid] = (ushort_t)m; A2[gid] = (ushort_t)l;
        if (k == 0) b1p[c] = (c < 50) ? b1[c] : 0.f;
    } else if (gid < 8192 + 7168) {
        int t = gid - 8192;
        int c = t >> 6, k = t & 63;
        float w = (c < 100 && k < 50) ? W2[k * 100 + c] : 0.f;
        uint32 h, m, l; split3(w, h, m, l);
        B0[t] = (ushort_t)h; B1[t] = (ushort_t)m; B2[t] = (ushort_t)l;
        if (k == 0) b2p[c] = (c < 100) ? b2[c] : 0.f;
    }
}

// ---------------------------------------------------------------- init h
__global__ void init_h_kernel(const float* __restrict__ feat, const float* __restrict__ W,
                              const float* __restrict__ b, float* __restrict__ Act) {
    int gid = blockIdx.x * 256 + threadIdx.x;   // N*100
    int n = gid / 100, d = gid - n * 100;
    float acc = b[d];
#pragma unroll
    for (int k = 0; k < 4; k++) acc += feat[n * 4 + k] * W[k * 100 + d];
    Act[(size_t)n * 200 + 100 + d] = acc;
}

// ---------------------------------------------------------------- msg MLP (MFMA)
// fm = relu(h @ W1 + b1) @ W2 + b2 ; computed transposed: D[c][n]
__global__ __launch_bounds__(256, 2) void msg_mfma(
    const float* __restrict__ Act,
    const ushort_t* __restrict__ A0, const ushort_t* __restrict__ A1,
    const ushort_t* __restrict__ A2, const float* __restrict__ b1p,
    const ushort_t* __restrict__ B0, const ushort_t* __restrict__ B1,
    const ushort_t* __restrict__ B2, const float* __restrict__ b2p,
    float* __restrict__ fm) {
    __shared__ ushort_t C1[3][64][72];
    const int tid = threadIdx.x;
    const int u = tid >> 6;          // wave = node tile
    const int lane = tid & 63;
    const int m = lane & 15, q = lane >> 4;
    const int n0 = blockIdx.x * 64;
    const int n = n0 + u * 16 + m;

    f32x4 z = {0.f, 0.f, 0.f, 0.f};
    f32x4 a1[4] = {z, z, z, z};

    for (int kc = 0; kc < 4; kc++) {
        int kb = kc * 32 + q * 8;
        const float* src = Act + (size_t)n * 200 + 100 + kb;
        float4 v0 = *(const float4*)src;
        float4 v1 = *(const float4*)(src + 4);
        float e[8] = {v0.x, v0.y, v0.z, v0.w, v1.x, v1.y, v1.z, v1.w};
        union { short8 s; uint32 u4[4]; } f0, f1, f2;
#pragma unroll
        for (int j = 0; j < 4; j++) {
            uint32 ha, ma, la, hb, mb, lb;
            split3(e[2 * j], ha, ma, la);
            split3(e[2 * j + 1], hb, mb, lb);
            f0.u4[j] = ha | (hb << 16);
            f1.u4[j] = ma | (mb << 16);
            f2.u4[j] = la | (lb << 16);
        }
#pragma unroll
        for (int t = 0; t < 4; t++) {
            int off = (t * 16 + m) * 128 + kc * 32 + q * 8;
            short8 w0 = *(const short8*)(A0 + off);
            short8 w1 = *(const short8*)(A1 + off);
            short8 w2 = *(const short8*)(A2 + off);
            a1[t] = mfma16(w0, f0.s, a1[t]);
            a1[t] = mfma16(w0, f1.s, a1[t]);
            a1[t] = mfma16(w1, f0.s, a1[t]);
            a1[t] = mfma16(w0, f2.s, a1[t]);
            a1[t] = mfma16(w2, f0.s, a1[t]);
            a1[t] = mfma16(w1, f1.s, a1[t]);
        }
    }
    // epilogue 1: relu + split -> LDS
#pragma unroll
    for (int t = 0; t < 4; t++) {
        int c0 = t * 16 + 4 * q;
        float4 bb = *(const float4*)&b1p[c0];
        float v0 = fmaxf(a1[t][0] + bb.x, 0.f);
        float v1 = fmaxf(a1[t][1] + bb.y, 0.f);
        float v2 = fmaxf(a1[t][2] + bb.z, 0.f);
        float v3 = fmaxf(a1[t][3] + bb.w, 0.f);
        uint32 h0, m0, l0, h1, m1, l1, h2, m2, l2, h3, m3, l3;
        split3(v0, h0, m0, l0); split3(v1, h1, m1, l1);
        split3(v2, h2, m2, l2); split3(v3, h3, m3, l3);
        int nl = u * 16 + m;
        *(uint2*)&C1[0][nl][c0] = make_uint2(h0 | (h1 << 16), h2 | (h3 << 16));
        *(uint2*)&C1[1][nl][c0] = make_uint2(m0 | (m1 << 16), m2 | (m3 << 16));
        *(uint2*)&C1[2][nl][c0] = make_uint2(l0 | (l1 << 16), l2 | (l3 << 16));
    }
    __syncthreads();

    f32x4 a2[7] = {z, z, z, z, z, z, z};
    for (int kc = 0; kc < 2; kc++) {
        int nl = u * 16 + m;
        short8 c0f = *(const short8*)&C1[0][nl][kc * 32 + q * 8];
        short8 c1f = *(const short8*)&C1[1][nl][kc * 32 + q * 8];
        short8 c2f = *(const short8*)&C1[2][nl][kc * 32 + q * 8];
#pragma unroll
        for (int t = 0; t < 7; t++) {
            int off = (t * 16 + m) * 64 + kc * 32 + q * 8;
            short8 w0 = *(const short8*)(B0 + off);
            short8 w1 = *(const short8*)(B1 + off);
            short8 w2 = *(const short8*)(B2 + off);
            a2[t] = mfma16(w0, c0f, a2[t]);
            a2[t] = mfma16(w0, c1f, a2[t]);
            a2[t] = mfma16(w1, c0f, a2[t]);
            a2[t] = mfma16(w0, c2f, a2[t]);
            a2[t] = mfma16(w2, c0f, a2[t]);
            a2[t] = mfma16(w1, c1f, a2[t]);
        }
    }
#pragma unroll
    for (int t = 0; t < 7; t++) {
        int c0 = t * 16 + 4 * q;
        if (c0 < 100) {
            float4 bb = *(const float4*)&b2p[c0];
            float4 o;
            o.x = a2[t][0] + bb.x; o.y = a2[t][1] + bb.y;
            o.z = a2[t][2] + bb.z; o.w = a2[t][3] + bb.w;
            *(float4*)&fm[(size_t)n * 100 + c0] = o;
        }
    }
}

// ---------------------------------------------------------------- gather (CSR)
__global__ void gather4(const float* __restrict__ fm, const int* __restrict__ ptr,
                        const int* __restrict__ idx, float* __restrict__ Act) {
    int gid = blockIdx.x * 256 + threadIdx.x;   // N*25
    int n = gid / 25, qq = (gid - n * 25) * 4;
    int s = (n == 0) ? 0 : ptr[n - 1];
    int e = ptr[n];
    float4 acc = {0.f, 0.f, 0.f, 0.f};
    for (int i = s; i < e; i++) {
        float4 v = *(const float4*)&fm[(size_t)idx[i] * 100 + qq];
        acc.x += v.x; acc.y += v.y; acc.z += v.z; acc.w += v.w;
    }
    *(float4*)&Act[(size_t)n * 200 + qq] = acc;
}

// ---------------------------------------------------------------- GRU (MFMA) v4
// 64-row blocks, 28 col-tiles (448 padded cols), 7 tiles/wave (ct = 4t+wave).
// NO LDS, NO per-kc barriers: each wave reads its activation fragments directly
// from global (L1/L2) and splits in-register; weights stream from L2 per tile.
// Product-major passes give MFMA dependency distance 28. Single __syncthreads
// before the in-place h write (intra-block RAW on Act[k>=100]).
__global__ __launch_bounds__(256, 2) void gru_mfma(
    float* __restrict__ Act,
    const ushort_t* __restrict__ W0, const ushort_t* __restrict__ W1,
    const ushort_t* __restrict__ W2, const float* __restrict__ bg) {
    const int tid = threadIdx.x;
    const int wave = tid >> 6;
    const int lane = tid & 63;
    const int m = lane & 15, q = lane >> 4;
    const int n0 = blockIdx.x * 64;

    f32x4 z = {0.f, 0.f, 0.f, 0.f};
    f32x4 acc[7][4];
#pragma unroll
    for (int t = 0; t < 7; t++)
#pragma unroll
        for (int rf = 0; rf < 4; rf++) acc[t][rf] = z;

    int woff[7];
#pragma unroll
    for (int t = 0; t < 7; t++)
        woff[t] = ((t * 4 + wave) * 16 + m) * 224 + q * 8;

    const float* abase = Act + (size_t)(n0 + m) * 200 + q * 8;

#define GPASS(Wreg, Fr)                                          \
    _Pragma("unroll")                                            \
    for (int t = 0; t < 7; t++) {                                \
        _Pragma("unroll")                                        \
        for (int rf = 0; rf < 4; rf++)                           \
            acc[t][rf] = mfma16(Wreg[t], Fr[rf], acc[t][rf]);    \
    }

    for (int kc = 0; kc < 7; kc++) {
        const int kb = kc * 32 + q * 8;
        const int ko = kc * 32;
        // load + split this wave's activation fragments (4 row-frags)
        short8 f0[4], f1[4], f2[4];
#pragma unroll
        for (int rf = 0; rf < 4; rf++) {
            float e[8];
            if (kb < 200) {
                const float* src = abase + (size_t)rf * 16 * 200 + ko;
                float4 v0 = *(const float4*)src;
                float4 v1 = *(const float4*)(src + 4);
                e[0] = v0.x; e[1] = v0.y; e[2] = v0.z; e[3] = v0.w;
                e[4] = v1.x; e[5] = v1.y; e[6] = v1.z; e[7] = v1.w;
            } else {
#pragma unroll
                for (int j = 0; j < 8; j++) e[j] = 0.f;
            }
            union { short8 s; uint32 u4[4]; } p0, p1, p2;
#pragma unroll
            for (int j = 0; j < 4; j++) {
                uint32 ha, ma, la, hb, mb, lb;
                split3(e[2 * j], ha, ma, la);
                split3(e[2 * j + 1], hb, mb, lb);
                p0.u4[j] = ha | (hb << 16);
                p1.u4[j] = ma | (mb << 16);
                p2.u4[j] = la | (lb << 16);
            }
            f0[rf] = p0.s; f1[rf] = p1.s; f2[rf] = p2.s;
        }

        short8 w[7];
#pragma unroll
        for (int t = 0; t < 7; t++) w[t] = *(const short8*)(W0 + woff[t] + ko);
        GPASS(w, f0);                       // w0*f0
        GPASS(w, f1);                       // w0*f1
        GPASS(w, f2);                       // w0*f2
#pragma unroll
        for (int t = 0; t < 7; t++) w[t] = *(const short8*)(W1 + woff[t] + ko);
        GPASS(w, f0);                       // w1*f0
        GPASS(w, f1);                       // w1*f1
#pragma unroll
        for (int t = 0; t < 7; t++) w[t] = *(const short8*)(W2 + woff[t] + ko);
        GPASS(w, f0);                       // w2*f0
    }
#undef GPASS

    __syncthreads();    // all reads of Act[k>=100] complete before h overwrite

    // epilogue: gates, in-place h update
#pragma unroll
    for (int t = 0; t < 7; t++) {
        const int ct = t * 4 + wave;        // 0..27
        const int d = ct * 4 + q;           // 0..111
        if (d < 100) {
            float4 b4 = *(const float4*)&bg[ct * 16 + 4 * q];
#pragma unroll
            for (int rf = 0; rf < 4; rf++) {
                int n = n0 + rf * 16 + m;
                float* hp = Act + (size_t)n * 200 + 100 + d;
                float hold = *hp;
                float rp = acc[t][rf][0] + b4.x;
                float zp = acc[t][rf][1] + b4.y;
                float np = acc[t][rf][2] + b4.z;
                float hh = acc[t][rf][3] + b4.w;
                float rr = 1.f / (1.f + __expf(-rp));
                float zz = 1.f / (1.f + __expf(-zp));
                float nw = tanhf(np + rr * hh);
                *hp = (1.f - zz) * nw + zz * hold;
            }
        }
    }
}

// ---------------------------------------------------------------- classifier
__global__ __launch_bounds__(256) void classifier(
    const float* __restrict__ Act, const float* __restrict__ W1,
    const float* __restrict__ b1, const float* __restrict__ W2,
    const float* __restrict__ b2, float* __restrict__ out) {
    __shared__ float Wc[3000];
    __shared__ float bc[30];
    __shared__ float w2[30];
    int tid = threadIdx.x;
    for (int i = tid; i < 3000; i += 256) Wc[i] = W1[i];
    if (tid < 30) { bc[tid] = b1[tid]; w2[tid] = W2[tid]; }
    __syncthreads();
    int n = blockIdx.x * 256 + tid;
    float a[30];
#pragma unroll
    for (int j = 0; j < 30; j++) a[j] = bc[j];
    for (int k = 0; k < 100; k++) {
        float hv = Act[(size_t)n * 200 + 100 + k];
#pragma unroll
        for (int j = 0; j < 30; j++) a[j] = fmaf(hv, Wc[k * 30 + j], a[j]);
    }
    float s = b2[0];
#pragma unroll
    for (int j = 0; j < 30; j++) s = fmaf(fmaxf(a[j], 0.f), w2[j], s);
    out[n] = s;
}

// ---------------------------------------------------------------- launch
extern "C" void kernel_launch(void* const* d_in, const int* in_sizes, int n_in,
                              void* d_out, int out_size, void* d_ws, size_t ws_size,
                              hipStream_t stream) {
    const float* feat     = (const float*)d_in[0];
    const int*   er       = (const int*)d_in[1];
    const int*   ec       = (const int*)d_in[2];
    const float* init_W   = (const float*)d_in[3];
    const float* init_b   = (const float*)d_in[4];
    const float* fmsg_W1  = (const float*)d_in[5];
    const float* fmsg_b1  = (const float*)d_in[6];
    const float* fmsg_W2  = (const float*)d_in[7];
    const float* fmsg_b2  = (const float*)d_in[8];
    const float* bmsg_W1  = (const float*)d_in[9];
    const float* bmsg_b1  = (const float*)d_in[10];
    const float* bmsg_W2  = (const float*)d_in[11];
    const float* bmsg_b2  = (const float*)d_in[12];
    const float* fgru_Wih = (const float*)d_in[13];
    const float* fgru_Whh = (const float*)d_in[14];
    const float* fgru_bih = (const float*)d_in[15];
    const float* fgru_bhh = (const float*)d_in[16];
    const float* bgru_Wih = (const float*)d_in[17];
    const float* bgru_Whh = (const float*)d_in[18];
    const float* bgru_bih = (const float*)d_in[19];
    const float* bgru_bhh = (const float*)d_in[20];
    const float* cls_W1   = (const float*)d_in[21];
    const float* cls_b1   = (const float*)d_in[22];
    const float* cls_W2   = (const float*)d_in[23];
    const float* cls_b2   = (const float*)d_in[24];
    float* out = (float*)d_out;

    float* ws = (float*)d_ws;
    size_t o = 0;
    float* Act = ws + o; o += (size_t)Nn * 200;       // [N][200] msg|h fp32
    float* fm  = ws + o; o += (size_t)Nn * 100;       // [N][100] fp32

    ushort_t* us = (ushort_t*)(ws + o);
    size_t uo = 0;
    ushort_t* fWg0 = us + uo; uo += 448 * 224;
    ushort_t* fWg1 = us + uo; uo += 448 * 224;
    ushort_t* fWg2 = us + uo; uo += 448 * 224;
    ushort_t* bWg0 = us + uo; uo += 448 * 224;
    ushort_t* bWg1 = us + uo; uo += 448 * 224;
    ushort_t* bWg2 = us + uo; uo += 448 * 224;
    ushort_t* fA0 = us + uo; uo += 8192;
    ushort_t* fA1 = us + uo; uo += 8192;
    ushort_t* fA2 = us + uo; uo += 8192;
    ushort_t* bA0 = us + uo; uo += 8192;
    ushort_t* bA1 = us + uo; uo += 8192;
    ushort_t* bA2 = us + uo; uo += 8192;
    ushort_t* fB0 = us + uo; uo += 7168;
    ushort_t* fB1 = us + uo; uo += 7168;
    ushort_t* fB2 = us + uo; uo += 7168;
    ushort_t* bB0 = us + uo; uo += 7168;
    ushort_t* bB1 = us + uo; uo += 7168;
    ushort_t* bB2 = us + uo; uo += 7168;     // uo even
    o += uo / 2;

    float* bgf  = ws + o; o += 448;
    float* bgb  = ws + o; o += 448;
    float* b1pf = ws + o; o += 64;
    float* b1pb = ws + o; o += 64;
    float* b2pf = ws + o; o += 112;
    float* b2pb = ws + o; o += 112;

    int* iws   = (int*)(ws + o);
    int* ptr_f = iws;                       // N+1
    int* ptr_b = ptr_f + (Nn + 1);          // N+1
    int* cnt   = ptr_b + (Nn + 1);          // 2N
    int* cnt_f = cnt;
    int* cnt_b = cnt + Nn;
    int* src_f = cnt + 2 * (size_t)Nn;      // E
    int* src_b = src_f + Ee;                // E

    size_t need = o * sizeof(float) +
                  (size_t)(2 * (Nn + 1) + 2 * Nn + 2 * Ee) * sizeof(int);
    if (ws_size < need) {
        diag_kernel<<<(Nn + 255) / 256, 256, 0, stream>>>(out, (float)ws_size);
        return;
    }

    // CSR build
    zero_ints<<<(2 * Nn + 255) / 256, 256, 0, stream>>>(cnt, 2 * Nn);
    hist_kernel<<<Ee / 256, 256, 0, stream>>>(er, ec, cnt_f, cnt_b);
    scan_kernel<<<1, 1024, 0, stream>>>(cnt_f, ptr_f, Nn);
    scan_kernel<<<1, 1024, 0, stream>>>(cnt_b, ptr_b, Nn);
    fill_kernel<<<Ee / 256, 256, 0, stream>>>(er, ec, ptr_f, ptr_b, src_f, src_b);

    // weight prep (split to 3 bf16 limbs)
    prep_gru_w<<<(448 * 224 + 255) / 256, 256, 0, stream>>>(
        fgru_Wih, fgru_Whh, fgru_bih, fgru_bhh, fWg0, fWg1, fWg2, bgf);
    prep_gru_w<<<(448 * 224 + 255) / 256, 256, 0, stream>>>(
        bgru_Wih, bgru_Whh, bgru_bih, bgru_bhh, bWg0, bWg1, bWg2, bgb);
    prep_msg_w<<<(15360 + 255) / 256, 256, 0, stream>>>(
        fmsg_W1, fmsg_b1, fmsg_W2, fmsg_b2, fA0, fA1, fA2, b1pf, fB0, fB1, fB2, b2pf);
    prep_msg_w<<<(15360 + 255) / 256, 256, 0, stream>>>(
        bmsg_W1, bmsg_b1, bmsg_W2, bmsg_b2, bA0, bA1, bA2, b1pb, bB0, bB1, bB2, b2pb);

    // h init
    init_h_kernel<<<(Nn * 100) / 256, 256, 0, stream>>>(feat, init_W, init_b, Act);

    const int gTile = Nn / 64;            // 2048 (msg)
    const int gGru  = Nn / 64;            // 2048 (gru, 64 rows/block)
    const int gGath = Nn * 25 / 256;      // 12800

    for (int rd = 0; rd < 20; rd++) {
        msg_mfma<<<gTile, 256, 0, stream>>>(Act, fA0, fA1, fA2, b1pf, fB0, fB1, fB2, b2pf, fm);
        gather4<<<gGath, 256, 0, stream>>>(fm, ptr_f, src_f, Act);
        gru_mfma<<<gGru, 256, 0, stream>>>(Act, fWg0, fWg1, fWg2, bgf);

        msg_mfma<<<gTile, 256, 0, stream>>>(Act, bA0, bA1, bA2, b1pb, bB0, bB1, bB2, b2pb, fm);
        gather4<<<gGath, 256, 0, stream>>>(fm, ptr_b, src_b, Act);
        gru_mfma<<<gGru, 256, 0, stream>>>(Act, bWg0, bWg1, bWg2, bgb);
    }

    classifier<<<Nn / 256, 256, 0, stream>>>(Act, cls_W1, cls_b1, cls_W2, cls_b2, out);
}